// Round 1
// baseline (122.916 us; speedup 1.0000x reference)
//
#include <hip/hip_runtime.h>
#include <float.h>

// Chamfer distance, fp32, N=M=16384.
// d(q,t) = |q|^2 + (|t|^2 - 2 q.t). Targets transformed in-kernel to SoA LDS
// (TX=-2x, TY=-2y, TZ=-2z, TW=|t|^2). Each wave register-caches NQ=16
// wave-uniform queries as packed (q,q) float2 pairs; lanes stream 2 targets
// each per step via ds_read_b64. Inner math: 3 v_pk_fma_f32 + 1 v_min3_f32
// per 2 targets per query = 2 VALU slots/pair.
//
// R1: occupancy fix. Previous config (256 thr, 64KB LDS, 512 blocks) pinned
// the machine at 2 waves/SIMD -> ~26% real VALU issue. Now 512-thread blocks
// of 8 waves: wave w = query-group (w&3) x target-half (w>>2). Same 64
// queries/block, same 2.0 slots/pair density, same 64KB LDS (2 x 2048-pt
// half-segments), but 16 waves/CU = 4 waves/SIMD (VGPR 108 <= 128). Halves
// merged in-block via LDS so the 512-partial layout is unchanged.

#define NPTS 16384
constexpr int NQ   = 16;            // queries per wave
constexpr int NW   = 8;             // waves per block (4 q-groups x 2 t-halves)
constexpr int QPB  = 64;            // queries per block
constexpr int SEGH = 2048;          // targets per half-segment (2^11)
constexpr int HALF = NPTS / 2;      // 8192 targets per half
constexpr int NBLK = NPTS / QPB;    // 256 blocks per direction

typedef float v2f __attribute__((ext_vector_type(2)));

__global__ __launch_bounds__(512, 4) void cd_main(const float* __restrict__ gt,
                                                  const float* __restrict__ gen,
                                                  float* __restrict__ part) {
    const int dir = blockIdx.y;                    // 0: gt->gen, 1: gen->gt
    const float* __restrict__ Q = dir ? gen : gt;
    const float* __restrict__ T = dir ? gt : gen;

    __shared__ float TX[2 * SEGH], TY[2 * SEGH], TZ[2 * SEGH], TW[2 * SEGH];
    __shared__ float wm[NW][NQ];

    const int lane = threadIdx.x & 63;
    const int wave = __builtin_amdgcn_readfirstlane(threadIdx.x >> 6);
    const int qg   = wave & 3;                     // query group 0..3
    const int th   = wave >> 2;                    // target half 0..1

    // Wave-uniform query block: NQ queries duplicated into packed pairs.
    const int qbase = blockIdx.x * QPB + qg * NQ;
    v2f qx[NQ], qy[NQ], qz[NQ];
    #pragma unroll
    for (int i = 0; i < NQ; ++i) {
        const float x = Q[3 * (qbase + i) + 0];
        const float y = Q[3 * (qbase + i) + 1];
        const float z = Q[3 * (qbase + i) + 2];
        qx[i] = (v2f){x, x};
        qy[i] = (v2f){y, y};
        qz[i] = (v2f){z, z};
    }

    float m[NQ];
    #pragma unroll
    for (int i = 0; i < NQ; ++i) m[i] = FLT_MAX;

    const int lbase = th * SEGH;                   // this wave's LDS half

    for (int s = 0; s < HALF; s += SEGH) {
        // Stage + transform one 2048-pt segment per half into SoA LDS.
        // p in [0,4096): p<2048 -> half 0 targets [s, s+2048),
        //                p>=2048 -> half 1 targets [HALF+s, HALF+s+2048).
        #pragma unroll
        for (int k = 0; k < (2 * SEGH) / 512; ++k) {
            const int p = k * 512 + threadIdx.x;
            const int g = (p >> 11) * HALF + s + (p & (SEGH - 1));
            const float x = T[3 * g + 0];
            const float y = T[3 * g + 1];
            const float z = T[3 * g + 2];
            TX[p] = -2.0f * x;
            TY[p] = -2.0f * y;
            TZ[p] = -2.0f * z;
            TW[p] = fmaf(x, x, fmaf(y, y, z * z));
        }
        __syncthreads();

        // Sweep: each step, lane handles 2 consecutive targets vs NQ queries.
        #pragma unroll 2
        for (int st = 0; st < SEGH; st += 128) {
            const int b = lbase + st + 2 * lane;
            const v2f tx = *(const v2f*)&TX[b];
            const v2f ty = *(const v2f*)&TY[b];
            const v2f tz = *(const v2f*)&TZ[b];
            const v2f tw = *(const v2f*)&TW[b];
            #pragma unroll
            for (int i = 0; i < NQ; ++i) {
                v2f d;
                asm("v_pk_fma_f32 %0, %1, %2, %3"
                    : "=v"(d) : "v"(qz[i]), "v"(tz), "v"(tw));
                asm("v_pk_fma_f32 %0, %1, %2, %0"
                    : "+v"(d) : "v"(qy[i]), "v"(ty));
                asm("v_pk_fma_f32 %0, %1, %2, %0"
                    : "+v"(d) : "v"(qx[i]), "v"(tx));
                m[i] = fminf(fminf(d.x, d.y), m[i]);   // -> v_min3_f32
            }
        }
        __syncthreads();
    }

    // Cross-lane min per query; lane 0 publishes per-wave mins to LDS.
    #pragma unroll
    for (int i = 0; i < NQ; ++i) {
        float v = m[i];
        #pragma unroll
        for (int off = 32; off > 0; off >>= 1)
            v = fminf(v, __shfl_down(v, off, 64));
        if (lane == 0) wm[wave][i] = v;
    }
    __syncthreads();

    // Wave 0: merge target halves, add |q|^2, sum the block's 64 queries.
    if (threadIdx.x < 64) {
        const int g = threadIdx.x >> 4;            // query group
        const int i = threadIdx.x & 15;            // query within group
        float v = fminf(wm[g][i], wm[g + 4][i]);
        const int q = blockIdx.x * QPB + g * NQ + i;
        const float x = Q[3 * q + 0];
        const float y = Q[3 * q + 1];
        const float z = Q[3 * q + 2];
        v += fmaf(x, x, fmaf(y, y, z * z));
        #pragma unroll
        for (int off = 32; off > 0; off >>= 1) v += __shfl_down(v, off, 64);
        if (threadIdx.x == 0) part[blockIdx.y * NBLK + blockIdx.x] = v;
    }
}

__global__ __launch_bounds__(512) void cd_reduce(const float* __restrict__ part,
                                                 float* __restrict__ out) {
    float v = part[threadIdx.x];                   // 512 partials, 512 threads
    #pragma unroll
    for (int off = 32; off > 0; off >>= 1) v += __shfl_down(v, off, 64);
    __shared__ float ws[8];
    const int lane = threadIdx.x & 63, w = threadIdx.x >> 6;
    if (lane == 0) ws[w] = v;
    __syncthreads();
    if (threadIdx.x == 0) {
        float s = 0.0f;
        #pragma unroll
        for (int i = 0; i < 8; ++i) s += ws[i];
        out[0] = s * (1.0f / (float)NPTS);
    }
}

extern "C" void kernel_launch(void* const* d_in, const int* in_sizes, int n_in,
                              void* d_out, int out_size, void* d_ws, size_t ws_size,
                              hipStream_t stream) {
    const float* gt  = (const float*)d_in[0];
    const float* gen = (const float*)d_in[1];
    float* part      = (float*)d_ws;               // 512 floats
    float* out       = (float*)d_out;

    dim3 grid(NBLK, 2);                            // 256 x 2 = 512 blocks
    cd_main<<<grid, 512, 0, stream>>>(gt, gen, part);
    cd_reduce<<<1, 512, 0, stream>>>(part, out);
}

// Round 3
// 100.151 us; speedup vs baseline: 1.2273x; 1.2273x over previous
//
#include <hip/hip_runtime.h>
#include <float.h>

// Chamfer distance, fp32, N=M=16384.
// d(q,t) = |q|^2 + (|t|^2 - 2 q.t). Targets transformed in-kernel to SoA LDS
// (TX=-2x, TY=-2y, TZ=-2z, TW=|t|^2). Each wave register-caches NQ=16
// wave-uniform queries PACKED 2-per-64b-pair ({q2i, q2i+1}); the VOP3P
// op_sel/op_sel_hi modifiers broadcast one half per FMA chain, so the query
// cache costs 48 VGPRs instead of R0's 96 duplicated pairs. Lanes stream 2
// targets each per step via ds_read_b64. Inner math per 2 targets x 2
// queries: 6 v_pk_fma_f32 + 2 v_min3_f32 = 2.0 VALU slots/pair (unchanged).
//
// R1 post-mortem: __launch_bounds__(512,4) + 96-reg duplicated query cache
// spilled (VGPR=64, 3MB scratch). R2 post-mortem: scalar floats are illegal
// v_pk_fma_f32 operands (sources must be 64-bit pairs). R3: packed-2-query
// pairs + op_sel halves — true demand ~90 regs, fits the 128 cap, keeps the
// 8-wave / 4-waves-per-SIMD occupancy AND the 2.0 slots/pair density.

#define NPTS 16384
constexpr int NQ   = 16;            // queries per wave
constexpr int NQP  = NQ / 2;        // query pairs per wave
constexpr int NW   = 8;             // waves per block (4 q-groups x 2 t-halves)
constexpr int QPB  = 64;            // queries per block
constexpr int SEGH = 2048;          // targets per half-segment (2^11)
constexpr int HALF = NPTS / 2;      // 8192 targets per half
constexpr int NBLK = NPTS / QPB;    // 256 blocks per direction

typedef float v2f __attribute__((ext_vector_type(2)));

__global__ __launch_bounds__(512, 4) void cd_main(const float* __restrict__ gt,
                                                  const float* __restrict__ gen,
                                                  float* __restrict__ part) {
    const int dir = blockIdx.y;                    // 0: gt->gen, 1: gen->gt
    const float* __restrict__ Q = dir ? gen : gt;
    const float* __restrict__ T = dir ? gt : gen;

    __shared__ float TX[2 * SEGH], TY[2 * SEGH], TZ[2 * SEGH], TW[2 * SEGH];
    __shared__ float wm[NW][NQ];

    const int lane = threadIdx.x & 63;
    const int wave = __builtin_amdgcn_readfirstlane(threadIdx.x >> 6);
    const int qg   = wave & 3;                     // query group 0..3
    const int th   = wave >> 2;                    // target half 0..1

    // Wave-uniform query block: 2 queries packed per 64-bit pair.
    const int qbase = blockIdx.x * QPB + qg * NQ;
    v2f qx[NQP], qy[NQP], qz[NQP];
    #pragma unroll
    for (int i = 0; i < NQP; ++i) {
        qx[i] = (v2f){Q[3 * (qbase + 2 * i) + 0], Q[3 * (qbase + 2 * i + 1) + 0]};
        qy[i] = (v2f){Q[3 * (qbase + 2 * i) + 1], Q[3 * (qbase + 2 * i + 1) + 1]};
        qz[i] = (v2f){Q[3 * (qbase + 2 * i) + 2], Q[3 * (qbase + 2 * i + 1) + 2]};
    }

    float m[NQ];
    #pragma unroll
    for (int i = 0; i < NQ; ++i) m[i] = FLT_MAX;

    const int lbase = th * SEGH;                   // this wave's LDS half

    for (int s = 0; s < HALF; s += SEGH) {
        // Stage + transform one 2048-pt segment per half into SoA LDS.
        // p in [0,4096): p<2048 -> half 0 targets [s, s+2048),
        //                p>=2048 -> half 1 targets [HALF+s, HALF+s+2048).
        #pragma unroll
        for (int k = 0; k < (2 * SEGH) / 512; ++k) {
            const int p = k * 512 + threadIdx.x;
            const int g = (p >> 11) * HALF + s + (p & (SEGH - 1));
            const float x = T[3 * g + 0];
            const float y = T[3 * g + 1];
            const float z = T[3 * g + 2];
            TX[p] = -2.0f * x;
            TY[p] = -2.0f * y;
            TZ[p] = -2.0f * z;
            TW[p] = fmaf(x, x, fmaf(y, y, z * z));
        }
        __syncthreads();

        // Sweep: each step, lane handles 2 consecutive targets vs NQ queries.
        #pragma unroll 2
        for (int st = 0; st < SEGH; st += 128) {
            const int b = lbase + st + 2 * lane;
            const v2f tx = *(const v2f*)&TX[b];
            const v2f ty = *(const v2f*)&TY[b];
            const v2f tz = *(const v2f*)&TZ[b];
            const v2f tw = *(const v2f*)&TW[b];
            #pragma unroll
            for (int i = 0; i < NQP; ++i) {
                // query 2i: broadcast lo half of the query pair.
                v2f d0;
                asm("v_pk_fma_f32 %0, %1, %2, %3 op_sel:[0,0,0] op_sel_hi:[0,1,1]"
                    : "=v"(d0) : "v"(qz[i]), "v"(tz), "v"(tw));
                asm("v_pk_fma_f32 %0, %1, %2, %0 op_sel:[0,0,0] op_sel_hi:[0,1,1]"
                    : "+v"(d0) : "v"(qy[i]), "v"(ty));
                asm("v_pk_fma_f32 %0, %1, %2, %0 op_sel:[0,0,0] op_sel_hi:[0,1,1]"
                    : "+v"(d0) : "v"(qx[i]), "v"(tx));
                m[2 * i] = fminf(fminf(d0.x, d0.y), m[2 * i]);      // v_min3_f32
                // query 2i+1: broadcast hi half of the query pair.
                v2f d1;
                asm("v_pk_fma_f32 %0, %1, %2, %3 op_sel:[1,0,0] op_sel_hi:[1,1,1]"
                    : "=v"(d1) : "v"(qz[i]), "v"(tz), "v"(tw));
                asm("v_pk_fma_f32 %0, %1, %2, %0 op_sel:[1,0,0] op_sel_hi:[1,1,1]"
                    : "+v"(d1) : "v"(qy[i]), "v"(ty));
                asm("v_pk_fma_f32 %0, %1, %2, %0 op_sel:[1,0,0] op_sel_hi:[1,1,1]"
                    : "+v"(d1) : "v"(qx[i]), "v"(tx));
                m[2 * i + 1] = fminf(fminf(d1.x, d1.y), m[2 * i + 1]);
            }
        }
        __syncthreads();
    }

    // Cross-lane min per query; lane 0 publishes per-wave mins to LDS.
    #pragma unroll
    for (int i = 0; i < NQ; ++i) {
        float v = m[i];
        #pragma unroll
        for (int off = 32; off > 0; off >>= 1)
            v = fminf(v, __shfl_down(v, off, 64));
        if (lane == 0) wm[wave][i] = v;
    }
    __syncthreads();

    // Wave 0: merge target halves, add |q|^2, sum the block's 64 queries.
    if (threadIdx.x < 64) {
        const int g = threadIdx.x >> 4;            // query group
        const int i = threadIdx.x & 15;            // query within group
        float v = fminf(wm[g][i], wm[g + 4][i]);
        const int q = blockIdx.x * QPB + g * NQ + i;
        const float x = Q[3 * q + 0];
        const float y = Q[3 * q + 1];
        const float z = Q[3 * q + 2];
        v += fmaf(x, x, fmaf(y, y, z * z));
        #pragma unroll
        for (int off = 32; off > 0; off >>= 1) v += __shfl_down(v, off, 64);
        if (threadIdx.x == 0) part[blockIdx.y * NBLK + blockIdx.x] = v;
    }
}

__global__ __launch_bounds__(512) void cd_reduce(const float* __restrict__ part,
                                                 float* __restrict__ out) {
    float v = part[threadIdx.x];                   // 512 partials, 512 threads
    #pragma unroll
    for (int off = 32; off > 0; off >>= 1) v += __shfl_down(v, off, 64);
    __shared__ float ws[8];
    const int lane = threadIdx.x & 63, w = threadIdx.x >> 6;
    if (lane == 0) ws[w] = v;
    __syncthreads();
    if (threadIdx.x == 0) {
        float s = 0.0f;
        #pragma unroll
        for (int i = 0; i < 8; ++i) s += ws[i];
        out[0] = s * (1.0f / (float)NPTS);
    }
}

extern "C" void kernel_launch(void* const* d_in, const int* in_sizes, int n_in,
                              void* d_out, int out_size, void* d_ws, size_t ws_size,
                              hipStream_t stream) {
    const float* gt  = (const float*)d_in[0];
    const float* gen = (const float*)d_in[1];
    float* part      = (float*)d_ws;               // 512 floats
    float* out       = (float*)d_out;

    dim3 grid(NBLK, 2);                            // 256 x 2 = 512 blocks
    cd_main<<<grid, 512, 0, stream>>>(gt, gen, part);
    cd_reduce<<<1, 512, 0, stream>>>(part, out);
}

// Round 4
// 98.712 us; speedup vs baseline: 1.2452x; 1.0146x over previous
//
#include <hip/hip_runtime.h>
#include <float.h>

// Chamfer distance, fp32, N=M=16384.
// d(q,t) = |q|^2 + (|t|^2 - 2 q.t). Targets transformed in-kernel to SoA LDS
// (TX=-2x, TY=-2y, TZ=-2z, TW=|t|^2). Queries are wave-uniform, so they live
// in SGPR pairs ({q2i, q2i+1} packed, op_sel selects the half) — v_pk_fma_f32
// takes exactly one scalar source, and the query is it. Lanes stream 2
// targets each per step via ds_read_b64, explicitly ping-pong-prefetched into
// registers so each step's 64-instr compute hides the other buffer's DS
// latency. Inner math per 2 targets x 2 queries: 6 v_pk_fma_f32 +
// 2 v_min3_f32 = 2.0 VALU lane-slots/pair.
//
// R3 post-mortem: VGPR_Count=56 vs ~90 true demand -> compiler parked the
// query/min arrays in AGPRs; the "v"-constrained asm then paid accvgpr
// shuttles every use (VALUBusy ~60% = 2.3x the 13.6us math floor, in BOTH
// the 2-wave and 4-wave configs; occupancy doubling changed nothing). R4
// moves the query cache to SGPRs ("s" constraints, ~48 SGPRs) so arch-VGPR
// demand is ~45, and adds register ping-pong on the target stream.

#define NPTS 16384
constexpr int NQ   = 16;            // queries per wave
constexpr int NQP  = NQ / 2;        // query pairs per wave
constexpr int NW   = 8;             // waves per block (4 q-groups x 2 t-halves)
constexpr int QPB  = 64;            // queries per block
constexpr int SEGH = 2048;          // targets per half-segment (2^11)
constexpr int HALF = NPTS / 2;      // 8192 targets per half
constexpr int NBLK = NPTS / QPB;    // 256 blocks per direction

typedef float v2f __attribute__((ext_vector_type(2)));

// 2 targets (packed pair) vs queries 2i / 2i+1 of the SGPR-resident cache.
#define CD_COMPUTE(tx, ty, tz, tw)                                            \
    _Pragma("unroll")                                                         \
    for (int i = 0; i < NQP; ++i) {                                           \
        v2f d0, d1;                                                           \
        asm("v_pk_fma_f32 %0, %1, %2, %3 op_sel:[0,0,0] op_sel_hi:[0,1,1]"    \
            : "=v"(d0) : "s"(qz[i]), "v"(tz), "v"(tw));                       \
        asm("v_pk_fma_f32 %0, %1, %2, %3 op_sel:[1,0,0] op_sel_hi:[1,1,1]"    \
            : "=v"(d1) : "s"(qz[i]), "v"(tz), "v"(tw));                       \
        asm("v_pk_fma_f32 %0, %1, %2, %0 op_sel:[0,0,0] op_sel_hi:[0,1,1]"    \
            : "+v"(d0) : "s"(qy[i]), "v"(ty));                                \
        asm("v_pk_fma_f32 %0, %1, %2, %0 op_sel:[1,0,0] op_sel_hi:[1,1,1]"    \
            : "+v"(d1) : "s"(qy[i]), "v"(ty));                                \
        asm("v_pk_fma_f32 %0, %1, %2, %0 op_sel:[0,0,0] op_sel_hi:[0,1,1]"    \
            : "+v"(d0) : "s"(qx[i]), "v"(tx));                                \
        asm("v_pk_fma_f32 %0, %1, %2, %0 op_sel:[1,0,0] op_sel_hi:[1,1,1]"    \
            : "+v"(d1) : "s"(qx[i]), "v"(tx));                                \
        m[2 * i]     = fminf(fminf(d0.x, d0.y), m[2 * i]);     /* v_min3 */   \
        m[2 * i + 1] = fminf(fminf(d1.x, d1.y), m[2 * i + 1]);                \
    }

__global__ __launch_bounds__(512, 4) void cd_main(const float* __restrict__ gt,
                                                  const float* __restrict__ gen,
                                                  float* __restrict__ part) {
    const int dir = blockIdx.y;                    // 0: gt->gen, 1: gen->gt
    const float* __restrict__ Q = dir ? gen : gt;
    const float* __restrict__ T = dir ? gt : gen;

    __shared__ float TX[2 * SEGH], TY[2 * SEGH], TZ[2 * SEGH], TW[2 * SEGH];
    __shared__ float wm[NW][NQ];

    const int lane = threadIdx.x & 63;
    const int wave = __builtin_amdgcn_readfirstlane(threadIdx.x >> 6);
    const int qg   = wave & 3;                     // query group 0..3
    const int th   = wave >> 2;                    // target half 0..1

    // Wave-uniform query block: 2 queries packed per 64-bit value. The "s"
    // asm constraints below keep these in SGPR pairs (hoisted by LICM).
    const int qbase = blockIdx.x * QPB + qg * NQ;
    v2f qx[NQP], qy[NQP], qz[NQP];
    #pragma unroll
    for (int i = 0; i < NQP; ++i) {
        qx[i] = (v2f){Q[3 * (qbase + 2 * i) + 0], Q[3 * (qbase + 2 * i + 1) + 0]};
        qy[i] = (v2f){Q[3 * (qbase + 2 * i) + 1], Q[3 * (qbase + 2 * i + 1) + 1]};
        qz[i] = (v2f){Q[3 * (qbase + 2 * i) + 2], Q[3 * (qbase + 2 * i + 1) + 2]};
    }

    float m[NQ];
    #pragma unroll
    for (int i = 0; i < NQ; ++i) m[i] = FLT_MAX;

    const int lbase = th * SEGH + 2 * lane;        // this wave's LDS half

    for (int s = 0; s < HALF; s += SEGH) {
        // Stage + transform one 2048-pt segment per half into SoA LDS.
        #pragma unroll
        for (int k = 0; k < (2 * SEGH) / 512; ++k) {
            const int p = k * 512 + threadIdx.x;
            const int g = (p >> 11) * HALF + s + (p & (SEGH - 1));
            const float x = T[3 * g + 0];
            const float y = T[3 * g + 1];
            const float z = T[3 * g + 2];
            TX[p] = -2.0f * x;
            TY[p] = -2.0f * y;
            TZ[p] = -2.0f * z;
            TW[p] = fmaf(x, x, fmaf(y, y, z * z));
        }
        __syncthreads();

        // Register ping-pong over the segment: while computing one 2-target
        // buffer, the other buffer's ds_reads are in flight.
        v2f atx = *(const v2f*)&TX[lbase], aty = *(const v2f*)&TY[lbase];
        v2f atz = *(const v2f*)&TZ[lbase], atw = *(const v2f*)&TW[lbase];
        for (int st = 0; st < SEGH; st += 256) {
            const int bb = lbase + st + 128;
            v2f btx = *(const v2f*)&TX[bb], bty = *(const v2f*)&TY[bb];
            v2f btz = *(const v2f*)&TZ[bb], btw = *(const v2f*)&TW[bb];
            CD_COMPUTE(atx, aty, atz, atw)
            const int ab = lbase + ((st + 256) & (SEGH - 1));  // wrap: dead on last iter
            atx = *(const v2f*)&TX[ab]; aty = *(const v2f*)&TY[ab];
            atz = *(const v2f*)&TZ[ab]; atw = *(const v2f*)&TW[ab];
            CD_COMPUTE(btx, bty, btz, btw)
        }
        __syncthreads();
    }

    // Cross-lane min per query; lane 0 publishes per-wave mins to LDS.
    #pragma unroll
    for (int i = 0; i < NQ; ++i) {
        float v = m[i];
        #pragma unroll
        for (int off = 32; off > 0; off >>= 1)
            v = fminf(v, __shfl_down(v, off, 64));
        if (lane == 0) wm[wave][i] = v;
    }
    __syncthreads();

    // Wave 0: merge target halves, add |q|^2, sum the block's 64 queries.
    if (threadIdx.x < 64) {
        const int g = threadIdx.x >> 4;            // query group
        const int i = threadIdx.x & 15;            // query within group
        float v = fminf(wm[g][i], wm[g + 4][i]);
        const int q = blockIdx.x * QPB + g * NQ + i;
        const float x = Q[3 * q + 0];
        const float y = Q[3 * q + 1];
        const float z = Q[3 * q + 2];
        v += fmaf(x, x, fmaf(y, y, z * z));
        #pragma unroll
        for (int off = 32; off > 0; off >>= 1) v += __shfl_down(v, off, 64);
        if (threadIdx.x == 0) part[blockIdx.y * NBLK + blockIdx.x] = v;
    }
}

__global__ __launch_bounds__(512) void cd_reduce(const float* __restrict__ part,
                                                 float* __restrict__ out) {
    float v = part[threadIdx.x];                   // 512 partials, 512 threads
    #pragma unroll
    for (int off = 32; off > 0; off >>= 1) v += __shfl_down(v, off, 64);
    __shared__ float ws[8];
    const int lane = threadIdx.x & 63, w = threadIdx.x >> 6;
    if (lane == 0) ws[w] = v;
    __syncthreads();
    if (threadIdx.x == 0) {
        float s = 0.0f;
        #pragma unroll
        for (int i = 0; i < 8; ++i) s += ws[i];
        out[0] = s * (1.0f / (float)NPTS);
    }
}

extern "C" void kernel_launch(void* const* d_in, const int* in_sizes, int n_in,
                              void* d_out, int out_size, void* d_ws, size_t ws_size,
                              hipStream_t stream) {
    const float* gt  = (const float*)d_in[0];
    const float* gen = (const float*)d_in[1];
    float* part      = (float*)d_ws;               // 512 floats
    float* out       = (float*)d_out;

    dim3 grid(NBLK, 2);                            // 256 x 2 = 512 blocks
    cd_main<<<grid, 512, 0, stream>>>(gt, gen, part);
    cd_reduce<<<1, 512, 0, stream>>>(part, out);
}

// Round 5
// 98.559 us; speedup vs baseline: 1.2471x; 1.0016x over previous
//
#include <hip/hip_runtime.h>
#include <float.h>

// Chamfer distance, fp32, N=M=16384.
// d(q,t) = |q|^2 + (|t|^2 - 2 q.t). Targets transformed in-kernel to SoA LDS
// (TX=-2x, TY=-2y, TZ=-2z, TW=|t|^2). Queries are wave-uniform -> SGPR pairs
// ({q2i,q2i+1} packed, op_sel picks the half; v_pk_fma_f32's one scalar
// source is the query). Lanes stream 4 targets per superstep via
// ds_read_b128 (conflict-free 4*lane pattern), double-buffered in registers.
//
// R4 post-mortem: 52us invariant across 2 vs 4 waves/SIMD, AGPR fix, and
// ping-pong => stalls are CORRELATED across waves (lockstep out of each
// barrier, same ds_read->lgkmcnt window at the same instant; ~40% idle that
// occupancy cannot fill). Also corrected floor: v_pk_fma_f32 is 4 cyc/wave64
// (157.3 TF = 1 FMA/lane/cyc; packed fp32 is NOT double-rate on CDNA4), so
// the VALU floor is ~24us, not 13.6. R5: (a) wave-phase STAGGER - wave qg
// starts its sweep at superstep qg*2 and wraps (min is order-independent),
// decorrelating DS bursts; (b) b128 reads halve DS instrs and double the
// compute run per wait window (448 exec cyc per 4-read batch).

#define NPTS 16384
constexpr int NQ   = 16;            // queries per wave
constexpr int NQP  = NQ / 2;        // query pairs per wave
constexpr int NW   = 8;             // waves per block (4 q-groups x 2 t-halves)
constexpr int QPB  = 64;            // queries per block
constexpr int SEGH = 2048;          // targets per half-segment
constexpr int NSS  = 8;             // supersteps per half-segment (256 targets each)
constexpr int HALF = NPTS / 2;      // 8192 targets per half
constexpr int NBLK = NPTS / QPB;    // 256 blocks per direction

typedef float v2f __attribute__((ext_vector_type(2)));
typedef float v4f __attribute__((ext_vector_type(4)));

// One query pair (SGPR) vs one packed 2-target group: 6 pk_fma.
#define CD_PAIR(d0, d1, txp, typ, tzp, twp, i)                                \
    asm("v_pk_fma_f32 %0, %1, %2, %3 op_sel:[0,0,0] op_sel_hi:[0,1,1]"        \
        : "=v"(d0) : "s"(qz[i]), "v"(tzp), "v"(twp));                         \
    asm("v_pk_fma_f32 %0, %1, %2, %3 op_sel:[1,0,0] op_sel_hi:[1,1,1]"        \
        : "=v"(d1) : "s"(qz[i]), "v"(tzp), "v"(twp));                         \
    asm("v_pk_fma_f32 %0, %1, %2, %0 op_sel:[0,0,0] op_sel_hi:[0,1,1]"        \
        : "+v"(d0) : "s"(qy[i]), "v"(typ));                                   \
    asm("v_pk_fma_f32 %0, %1, %2, %0 op_sel:[1,0,0] op_sel_hi:[1,1,1]"        \
        : "+v"(d1) : "s"(qy[i]), "v"(typ));                                   \
    asm("v_pk_fma_f32 %0, %1, %2, %0 op_sel:[0,0,0] op_sel_hi:[0,1,1]"        \
        : "+v"(d0) : "s"(qx[i]), "v"(txp));                                   \
    asm("v_pk_fma_f32 %0, %1, %2, %0 op_sel:[1,0,0] op_sel_hi:[1,1,1]"        \
        : "+v"(d1) : "s"(qx[i]), "v"(txp));

// 4 targets (v4f regs) vs all NQ queries: 96 pk_fma + 32 min3.
#define CD_COMPUTE4(tx4, ty4, tz4, tw4)                                       \
    {                                                                         \
        const v2f txa = __builtin_shufflevector(tx4, tx4, 0, 1);              \
        const v2f txb = __builtin_shufflevector(tx4, tx4, 2, 3);              \
        const v2f tya = __builtin_shufflevector(ty4, ty4, 0, 1);              \
        const v2f tyb = __builtin_shufflevector(ty4, ty4, 2, 3);              \
        const v2f tza = __builtin_shufflevector(tz4, tz4, 0, 1);              \
        const v2f tzb = __builtin_shufflevector(tz4, tz4, 2, 3);              \
        const v2f twa = __builtin_shufflevector(tw4, tw4, 0, 1);              \
        const v2f twb = __builtin_shufflevector(tw4, tw4, 2, 3);              \
        _Pragma("unroll")                                                     \
        for (int i = 0; i < NQP; ++i) {                                       \
            v2f d0a, d1a, d0b, d1b;                                           \
            CD_PAIR(d0a, d1a, txa, tya, tza, twa, i)                          \
            CD_PAIR(d0b, d1b, txb, tyb, tzb, twb, i)                          \
            m[2 * i]     = fminf(fminf(d0a.x, d0a.y), m[2 * i]);              \
            m[2 * i]     = fminf(fminf(d0b.x, d0b.y), m[2 * i]);              \
            m[2 * i + 1] = fminf(fminf(d1a.x, d1a.y), m[2 * i + 1]);          \
            m[2 * i + 1] = fminf(fminf(d1b.x, d1b.y), m[2 * i + 1]);          \
        }                                                                     \
    }

__global__ __launch_bounds__(512, 4) void cd_main(const float* __restrict__ gt,
                                                  const float* __restrict__ gen,
                                                  float* __restrict__ part) {
    const int dir = blockIdx.y;                    // 0: gt->gen, 1: gen->gt
    const float* __restrict__ Q = dir ? gen : gt;
    const float* __restrict__ T = dir ? gt : gen;

    __shared__ float TX[2 * SEGH], TY[2 * SEGH], TZ[2 * SEGH], TW[2 * SEGH];
    __shared__ float wm[NW][NQ];

    const int lane = threadIdx.x & 63;
    const int wave = __builtin_amdgcn_readfirstlane(threadIdx.x >> 6);
    const int qg   = wave & 3;                     // query group 0..3
    const int th   = wave >> 2;                    // target half 0..1

    // Wave-uniform query block: 2 queries packed per 64-bit value, kept in
    // SGPR pairs by the "s" asm constraints (hoisted by LICM).
    const int qbase = blockIdx.x * QPB + qg * NQ;
    v2f qx[NQP], qy[NQP], qz[NQP];
    #pragma unroll
    for (int i = 0; i < NQP; ++i) {
        qx[i] = (v2f){Q[3 * (qbase + 2 * i) + 0], Q[3 * (qbase + 2 * i + 1) + 0]};
        qy[i] = (v2f){Q[3 * (qbase + 2 * i) + 1], Q[3 * (qbase + 2 * i + 1) + 1]};
        qz[i] = (v2f){Q[3 * (qbase + 2 * i) + 2], Q[3 * (qbase + 2 * i + 1) + 2]};
    }

    float m[NQ];
    #pragma unroll
    for (int i = 0; i < NQ; ++i) m[i] = FLT_MAX;

    // This wave's LDS half + its stagger phase (wave qg starts at superstep
    // qg*2 of 8 and wraps; min-accumulation is coverage-order independent).
    const int base  = th * SEGH + 4 * lane;
    const int start = qg * 2;

    for (int s = 0; s < HALF; s += SEGH) {
        // Stage + transform one 2048-pt segment per half into SoA LDS.
        #pragma unroll
        for (int k = 0; k < (2 * SEGH) / 512; ++k) {
            const int p = k * 512 + threadIdx.x;
            const int g = (p >> 11) * HALF + s + (p & (SEGH - 1));
            const float x = T[3 * g + 0];
            const float y = T[3 * g + 1];
            const float z = T[3 * g + 2];
            TX[p] = -2.0f * x;
            TY[p] = -2.0f * y;
            TZ[p] = -2.0f * z;
            TW[p] = fmaf(x, x, fmaf(y, y, z * z));
        }
        __syncthreads();

        // Staggered superstep sweep, register double-buffered b128 loads.
        {
            int offA = base + start * 256;
            v4f atx = *(const v4f*)&TX[offA], aty = *(const v4f*)&TY[offA];
            v4f atz = *(const v4f*)&TZ[offA], atw = *(const v4f*)&TW[offA];
            for (int j = 0; j < NSS; j += 2) {
                const int offB = base + (((start + j + 1) & (NSS - 1)) * 256);
                v4f btx = *(const v4f*)&TX[offB], bty = *(const v4f*)&TY[offB];
                v4f btz = *(const v4f*)&TZ[offB], btw = *(const v4f*)&TW[offB];
                CD_COMPUTE4(atx, aty, atz, atw)
                const int offA2 = base + (((start + j + 2) & (NSS - 1)) * 256);
                atx = *(const v4f*)&TX[offA2]; aty = *(const v4f*)&TY[offA2];
                atz = *(const v4f*)&TZ[offA2]; atw = *(const v4f*)&TW[offA2];
                CD_COMPUTE4(btx, bty, btz, btw)
            }
        }
        __syncthreads();
    }

    // Cross-lane min per query; lane 0 publishes per-wave mins to LDS.
    #pragma unroll
    for (int i = 0; i < NQ; ++i) {
        float v = m[i];
        #pragma unroll
        for (int off = 32; off > 0; off >>= 1)
            v = fminf(v, __shfl_down(v, off, 64));
        if (lane == 0) wm[wave][i] = v;
    }
    __syncthreads();

    // Wave 0: merge target halves, add |q|^2, sum the block's 64 queries.
    if (threadIdx.x < 64) {
        const int g = threadIdx.x >> 4;            // query group
        const int i = threadIdx.x & 15;            // query within group
        float v = fminf(wm[g][i], wm[g + 4][i]);
        const int q = blockIdx.x * QPB + g * NQ + i;
        const float x = Q[3 * q + 0];
        const float y = Q[3 * q + 1];
        const float z = Q[3 * q + 2];
        v += fmaf(x, x, fmaf(y, y, z * z));
        #pragma unroll
        for (int off = 32; off > 0; off >>= 1) v += __shfl_down(v, off, 64);
        if (threadIdx.x == 0) part[blockIdx.y * NBLK + blockIdx.x] = v;
    }
}

__global__ __launch_bounds__(512) void cd_reduce(const float* __restrict__ part,
                                                 float* __restrict__ out) {
    float v = part[threadIdx.x];                   // 512 partials, 512 threads
    #pragma unroll
    for (int off = 32; off > 0; off >>= 1) v += __shfl_down(v, off, 64);
    __shared__ float ws[8];
    const int lane = threadIdx.x & 63, w = threadIdx.x >> 6;
    if (lane == 0) ws[w] = v;
    __syncthreads();
    if (threadIdx.x == 0) {
        float s = 0.0f;
        #pragma unroll
        for (int i = 0; i < 8; ++i) s += ws[i];
        out[0] = s * (1.0f / (float)NPTS);
    }
}

extern "C" void kernel_launch(void* const* d_in, const int* in_sizes, int n_in,
                              void* d_out, int out_size, void* d_ws, size_t ws_size,
                              hipStream_t stream) {
    const float* gt  = (const float*)d_in[0];
    const float* gen = (const float*)d_in[1];
    float* part      = (float*)d_ws;               // 512 floats
    float* out       = (float*)d_out;

    dim3 grid(NBLK, 2);                            // 256 x 2 = 512 blocks
    cd_main<<<grid, 512, 0, stream>>>(gt, gen, part);
    cd_reduce<<<1, 512, 0, stream>>>(part, out);
}